// Round 5
// baseline (2060.658 us; speedup 1.0000x reference)
//
#include <hip/hip_runtime.h>
#include <hip/hip_bf16.h>
#include <stdint.h>

// MHSA with RPE on gfx950 — fp32 in/out per the reference.
// Internals: bf16 NT GEMMs (both operands [out_idx][k], k-contiguous) on
// v_mfma_f32_16x16x32_bf16; fp32->bf16 conversion kernels for x and weights.
//
// Per-(b,h) padded matrices: 196 rows x 224 cols bf16 (448 B rows).
//   Q  [n][d]   K  [m][d]   Qt [d][n] (+lo)   Vt [d][m]
//   CP [p][kd] hi+lo        S [n][m] fp32 (softmax in place, pads zeroed)
// pos = CP*Qt^T in split-bf16 (hi*hi + hi*lo + lo*hi): pos logits sigma~11,
// plain bf16 would cost ~0.05 abs logit error.  Batch processed in chunks CB
// sized to ws_size (CB=128 -> ~399 MB, CB=64 -> ~202 MB).

using bf16 = __hip_bfloat16;
typedef __bf16   bf16x8 __attribute__((ext_vector_type(8)));
typedef __bf16   bf16x4 __attribute__((ext_vector_type(4)));
typedef float    f32x4  __attribute__((ext_vector_type(4)));
typedef uint32_t u32x4  __attribute__((ext_vector_type(4)));

#define NROW 196
#define PADN 224
#define MATE (NROW*PADN)     // 43,904 elems per per-head matrix
#define MATB2 (MATE*2)       // 87,808 bytes (bf16)

// Stage a 128-row x 64-byte (32 bf16 cols) tile into an 8 KB LDS buffer via
// registers.  Rows > maxRow are ZERO-FILLED.  LDS: flat row*64 + boff.
__device__ __forceinline__ void stage_reg(const char* g0, int rowBytes,
                                          int maxRow, char* buf, int tid) {
#pragma unroll
  for (int r = 0; r < 2; ++r) {
    const int flat = r * 4096 + tid * 16;
    const int row = flat >> 6;
    const int boff = flat & 63;
    u32x4 v = {0u, 0u, 0u, 0u};
    if (row <= maxRow) v = *(const u32x4*)(g0 + (size_t)row * rowBytes + boff);
    *(u32x4*)(buf + flat) = v;
  }
}

// One BK=32 step: 4 A-frags + 4 B-frags (ds_read_b128) + 16 MFMA.
// A-frag: lane holds A[m=lane&15][k=(lane>>4)*8+j]; B identical with n.
__device__ __forceinline__ void mfma_tiles(const char* bufA, const char* bufB,
                                           f32x4 (&acc)[4][4], int wr, int wc,
                                           int lane) {
  const int q = lane >> 4, c = lane & 15;
  bf16x8 a[4], b[4];
#pragma unroll
  for (int i = 0; i < 4; ++i)
    a[i] = *(const bf16x8*)(bufA + ((wr * 64 + i * 16 + c) << 6) + (q << 4));
#pragma unroll
  for (int j = 0; j < 4; ++j)
    b[j] = *(const bf16x8*)(bufB + ((wc * 64 + j * 16 + c) << 6) + (q << 4));
#pragma unroll
  for (int i = 0; i < 4; ++i)
#pragma unroll
    for (int j = 0; j < 4; ++j)
      acc[i][j] = __builtin_amdgcn_mfma_f32_16x16x32_bf16(a[i], b[j], acc[i][j], 0, 0, 0);
}

__device__ __forceinline__ void gemm_pass(const char* A, const char* B,
                                          int maxA, int maxB, int rowBytes, int nk,
                                          f32x4 (&acc)[4][4], char* bufA, char* bufB,
                                          int tid, int wr, int wc, int lane) {
  for (int kc = 0; kc < nk; ++kc) {
    stage_reg(A + kc * 64, rowBytes, maxA, bufA, tid);
    stage_reg(B + kc * 64, rowBytes, maxB, bufB, tid);
    __syncthreads();
    mfma_tiles(bufA, bufB, acc, wr, wc, lane);
    __syncthreads();
  }
}

// ---------------- projection GEMM: out[m,o] = sum_c A[m,c] * W[o,c] + b[o] --
// M = CB*196, N = 784, K = 784 (24 chunks + masked 16-col tail).
// EPI 0: Q -> head-split + Qt hi/lo transposed copies
// EPI 1: K -> head-split       EPI 2: V -> transposed (Vt)
// EPI 3: final -> fp32 d_out
template <int EPI>
__global__ __launch_bounds__(256) void gemm_proj(
    const bf16* __restrict__ A, const bf16* __restrict__ W,
    const float* __restrict__ bias, bf16* __restrict__ dst1,
    bf16* __restrict__ dst2, bf16* __restrict__ dst3,
    float* __restrict__ dstF, int M) {
  __shared__ __align__(16) char smem[16384];
  char* bufA = smem;
  char* bufB = smem + 8192;
  const int tid = threadIdx.x, lane = tid & 63, wave = tid >> 6;
  const int wr = wave >> 1, wc = wave & 1;
  const int m0 = blockIdx.x * 128, n0 = blockIdx.y * 128;
  const int maxA = M - 1 - m0;
  const int maxB = 783 - n0;

  f32x4 acc[4][4];
  const f32x4 z4 = {0.f, 0.f, 0.f, 0.f};
#pragma unroll
  for (int i = 0; i < 4; ++i)
#pragma unroll
    for (int j = 0; j < 4; ++j) acc[i][j] = z4;

  const char* Ab = (const char*)A + (size_t)m0 * 1568;  // 784 bf16 = 1568 B
  const char* Bb = (const char*)W + (size_t)n0 * 1568;

  gemm_pass(Ab, Bb, maxA, maxB, 1568, 24, acc, bufA, bufB, tid, wr, wc, lane);

  {  // K tail: k = 768..783 (first 32 B of each row's last 64 B window)
#pragma unroll
    for (int r = 0; r < 2; ++r) {
      const int flat = r * 4096 + tid * 16;
      const int row = flat >> 6;
      const int boff = flat & 63;
      u32x4 va = {0u, 0u, 0u, 0u}, vb = {0u, 0u, 0u, 0u};
      if (boff < 32) {
        if (row <= maxA)
          va = *(const u32x4*)(Ab + (size_t)row * 1568 + 1536 + boff);
        if (row <= maxB)
          vb = *(const u32x4*)(Bb + (size_t)row * 1568 + 1536 + boff);
      }
      *(u32x4*)(bufA + flat) = va;
      *(u32x4*)(bufB + flat) = vb;
    }
    __syncthreads();
    mfma_tiles(bufA, bufB, acc, wr, wc, lane);
  }

  // Epilogue.  C/D layout: col = lane&15, row = (lane>>4)*4 + reg  [m89].
  const int q = lane >> 4, c = lane & 15;
#pragma unroll
  for (int j = 0; j < 4; ++j) {
    const int col = n0 + wc * 64 + j * 16 + c;
    if (col >= 784) continue;
    const float bs = bias[col];
    const int hh = col / 196, dd = col - (col / 196) * 196;
#pragma unroll
    for (int i = 0; i < 4; ++i) {
#pragma unroll
      for (int r = 0; r < 4; ++r) {
        const int row = m0 + wr * 64 + i * 16 + q * 4 + r;
        if (row >= M) continue;
        const float v = acc[i][j][r] + bs;
        if (EPI == 3) {
          dstF[(size_t)row * 784 + col] = v;
        } else {
          const int b = row / 196, n = row - (row / 196) * 196;  // chunk-local
          const size_t base = (size_t)(b * 4 + hh) * MATE;
          const bf16 hv = __float2bfloat16(v);
          if (EPI == 0) {
            dst1[base + n * PADN + dd] = hv;                     // Q [n][d]
            dst2[base + dd * PADN + n] = hv;                     // Qt hi [d][n]
            const float lo = v - __bfloat162float(hv);
            dst3[base + dd * PADN + n] = __float2bfloat16(lo);   // Qt lo
          } else if (EPI == 1) {
            dst1[base + n * PADN + dd] = hv;                     // K [m][d]
          } else {
            dst2[base + dd * PADN + n] = hv;                     // Vt [d][m]
          }
        }
      }
    }
  }
}

// ------ scores: S = (Q K^T)/14 + CPhi*Qthi^T + CPhi*Qtlo^T + CPlo*Qthi^T ----
__global__ __launch_bounds__(256) void attn_score(
    const bf16* __restrict__ Q, const bf16* __restrict__ K,
    const bf16* __restrict__ CPh, const bf16* __restrict__ CPl,
    const bf16* __restrict__ Qth, const bf16* __restrict__ Qtl,
    float* __restrict__ S) {
  __shared__ __align__(16) char smem[16384];
  char* bufA = smem;
  char* bufB = smem + 8192;
  const int tid = threadIdx.x, lane = tid & 63, wave = tid >> 6;
  const int wr = wave >> 1, wc = wave & 1;
  const int bh = blockIdx.z, h = bh & 3;
  const int m0 = blockIdx.x * 128, n0 = blockIdx.y * 128;
  const int maxA = 195 - m0, maxB = 195 - n0;

  f32x4 acc[4][4];
  const f32x4 z4 = {0.f, 0.f, 0.f, 0.f};
#pragma unroll
  for (int i = 0; i < 4; ++i)
#pragma unroll
    for (int j = 0; j < 4; ++j) acc[i][j] = z4;

  const size_t bhB = (size_t)bh * MATB2, hB = (size_t)h * MATB2;
  const size_t am = (size_t)m0 * 448, bn = (size_t)n0 * 448;

  gemm_pass((const char*)Q + bhB + am, (const char*)K + bhB + bn,
            maxA, maxB, 448, 7, acc, bufA, bufB, tid, wr, wc, lane);
#pragma unroll
  for (int i = 0; i < 4; ++i)
#pragma unroll
    for (int j = 0; j < 4; ++j) acc[i][j] = acc[i][j] * (1.0f / 14.0f);

  gemm_pass((const char*)CPh + hB + am, (const char*)Qth + bhB + bn,
            maxA, maxB, 448, 7, acc, bufA, bufB, tid, wr, wc, lane);
  gemm_pass((const char*)CPh + hB + am, (const char*)Qtl + bhB + bn,
            maxA, maxB, 448, 7, acc, bufA, bufB, tid, wr, wc, lane);
  gemm_pass((const char*)CPl + hB + am, (const char*)Qth + bhB + bn,
            maxA, maxB, 448, 7, acc, bufA, bufB, tid, wr, wc, lane);

  float* Sb = S + (size_t)bh * MATE;
  const int q = lane >> 4, c = lane & 15;
#pragma unroll
  for (int i = 0; i < 4; ++i)
#pragma unroll
    for (int j = 0; j < 4; ++j)
#pragma unroll
      for (int r = 0; r < 4; ++r) {
        const int row = m0 + wr * 64 + i * 16 + q * 4 + r;
        const int col = n0 + wc * 64 + j * 16 + c;
        if (row < 196 && col < 224) Sb[row * PADN + col] = acc[i][j][r];
      }
}

// ------------- softmax over cols, in place, zero the col pads --------------
__global__ __launch_bounds__(256) void softmax_k(float* __restrict__ S) {
  const int bh = blockIdx.y;
  const int row = blockIdx.x * 4 + (threadIdx.x >> 6);  // 49*4 = 196 rows
  const int lane = threadIdx.x & 63;
  float* Sr = S + (size_t)bh * MATE + (size_t)row * PADN;
  float v[4];
  float mx = -1e30f;
#pragma unroll
  for (int k = 0; k < 4; ++k) {
    const int m = lane + k * 64;
    v[k] = (m < 196) ? Sr[m] : -1e30f;
    mx = fmaxf(mx, v[k]);
  }
#pragma unroll
  for (int off = 32; off; off >>= 1) mx = fmaxf(mx, __shfl_xor(mx, off));
  float s = 0.f;
#pragma unroll
  for (int k = 0; k < 4; ++k) {
    const int m = lane + k * 64;
    v[k] = (m < 196) ? __expf(v[k] - mx) : 0.f;
    s += v[k];
  }
#pragma unroll
  for (int off = 32; off; off >>= 1) s += __shfl_xor(s, off);
  const float inv = 1.0f / s;
#pragma unroll
  for (int k = 0; k < 4; ++k) {
    const int m = lane + k * 64;
    if (m < 224) Sr[m] = (m < 196) ? v[k] * inv : 0.f;
  }
}

// -------------------- O[n,d] = sum_m P[n,m] Vt[d,m] ------------------------
__global__ __launch_bounds__(256) void attn_pv(const float* __restrict__ S,
                                               const bf16* __restrict__ Vt,
                                               bf16* __restrict__ O) {
  __shared__ __align__(16) char smem[16384];
  char* bufA = smem;
  char* bufB = smem + 8192;
  const int tid = threadIdx.x, lane = tid & 63, wave = tid >> 6;
  const int wr = wave >> 1, wc = wave & 1;
  const int bh = blockIdx.z;
  const int m0 = blockIdx.x * 128, n0 = blockIdx.y * 128;
  const int maxA = 195 - m0, maxB = 195 - n0;

  f32x4 acc[4][4];
  const f32x4 z4 = {0.f, 0.f, 0.f, 0.f};
#pragma unroll
  for (int i = 0; i < 4; ++i)
#pragma unroll
    for (int j = 0; j < 4; ++j) acc[i][j] = z4;

  const char* Pb = (const char*)S + (size_t)bh * (MATE * 4) + (size_t)m0 * 896;
  const char* Bb = (const char*)Vt + (size_t)bh * MATB2 + (size_t)n0 * 448;

  for (int kc = 0; kc < 7; ++kc) {
    // A: fp32 attn weights -> bf16, register staging; OOB rows zero-filled.
#pragma unroll
    for (int r = 0; r < 2; ++r) {
      const int flat = r * 4096 + tid * 16;
      const int row = flat >> 6;
      const int boff = flat & 63;
      f32x4 fa = {0.f, 0.f, 0.f, 0.f}, fb = {0.f, 0.f, 0.f, 0.f};
      if (row <= maxA) {
        const char* src = Pb + (size_t)row * 896 + kc * 128 + boff * 2;
        fa = *(const f32x4*)src;
        fb = *(const f32x4*)(src + 16);
      }
      bf16x8 o8;
      o8[0] = (__bf16)fa[0]; o8[1] = (__bf16)fa[1];
      o8[2] = (__bf16)fa[2]; o8[3] = (__bf16)fa[3];
      o8[4] = (__bf16)fb[0]; o8[5] = (__bf16)fb[1];
      o8[6] = (__bf16)fb[2]; o8[7] = (__bf16)fb[3];
      *(bf16x8*)(bufA + flat) = o8;
    }
    stage_reg(Bb + kc * 64, 448, maxB, bufB, tid);
    __syncthreads();
    mfma_tiles(bufA, bufB, acc, wr, wc, lane);
    __syncthreads();
  }

  const int q = lane >> 4, c = lane & 15;
  const int b = bh >> 2, h = bh & 3;
#pragma unroll
  for (int i = 0; i < 4; ++i)
#pragma unroll
    for (int j = 0; j < 4; ++j)
#pragma unroll
      for (int r = 0; r < 4; ++r) {
        const int n = m0 + wr * 64 + i * 16 + q * 4 + r;
        const int d = n0 + wc * 64 + j * 16 + c;
        if (n < 196 && d < 196)
          O[(size_t)(b * 196 + n) * 784 + h * 196 + d] =
              __float2bfloat16(acc[i][j][r]);
      }
}

// -------------------- small prep kernels -----------------------------------
// CP[h][p][kd] = rel_h[h,kd,p/14] + rel_w[h,kd,p%14] (fp32 in), hi/lo split.
__global__ void build_cp(const float* __restrict__ rh, const float* __restrict__ rw,
                         bf16* __restrict__ CPh, bf16* __restrict__ CPl) {
  const int idx = blockIdx.x * 256 + threadIdx.x;  // < 4*43904 = 175,616
  if (idx >= 4 * MATE) return;
  const int h = idx / MATE;
  const int rem = idx - h * MATE;
  const int p = rem / PADN, kd = rem - (rem / PADN) * PADN;
  float v = 0.f;
  if (kd < 196) {
    const int gh = p / 14, gw = p - (p / 14) * 14;
    v = rh[(h * 196 + kd) * 14 + gh] + rw[(h * 196 + kd) * 14 + gw];
  }
  const bf16 hv = __float2bfloat16(v);
  CPh[idx] = hv;
  CPl[idx] = __float2bfloat16(v - __bfloat162float(hv));
}

// Zero the 28-col pad strip (56 B = 14 u32) of every 448 B row in the five
// contiguous chunk buffers (Q, K, Qth, Vt, Qtl).
__global__ void zero_pads(char* __restrict__ base, long nwords) {
  const long g = (long)blockIdx.x * 256 + threadIdx.x;
  if (g >= nwords) return;
  const long rowg = g / 14;
  const int cu = (int)(g - rowg * 14);
  *(uint32_t*)(base + rowg * 448 + 392 + cu * 4) = 0u;
}

// fp32 -> bf16, 4 elements per thread (total must be a multiple of 4).
__global__ void cvt_f2b(const float* __restrict__ src, bf16* __restrict__ dst,
                        long n4) {
  const long t = (long)blockIdx.x * 256 + threadIdx.x;
  if (t >= n4) return;
  const long i = t * 4;
  const f32x4 v = *(const f32x4*)(src + i);
  bf16x4 o;
  o[0] = (__bf16)v[0];
  o[1] = (__bf16)v[1];
  o[2] = (__bf16)v[2];
  o[3] = (__bf16)v[3];
  *(bf16x4*)(dst + i) = o;  // one 8 B store
}

extern "C" void kernel_launch(void* const* d_in, const int* in_sizes, int n_in,
                              void* d_out, int out_size, void* d_ws, size_t ws_size,
                              hipStream_t stream) {
  const float* x  = (const float*)d_in[0];
  const float* Wq = (const float*)d_in[1];
  const float* bq = (const float*)d_in[2];
  const float* Wk = (const float*)d_in[3];
  const float* bk = (const float*)d_in[4];
  const float* Wv = (const float*)d_in[5];
  const float* bv = (const float*)d_in[6];
  const float* Wo = (const float*)d_in[7];
  const float* bo = (const float*)d_in[8];
  const float* rh = (const float*)d_in[9];
  const float* rw = (const float*)d_in[10];
  float* out = (float*)d_out;

  // Per-batch-item bytes: 5 bf16 mats + XB + S fp32 + O.
  const size_t perHeadB = (size_t)MATB2;           // 87,808
  const size_t perB5 = 5 * 4 * perHeadB;           // 1,756,160
  const size_t perBX = (size_t)196 * 784 * 2;      // 307,328 (x chunk, bf16)
  const size_t perBS = 4 * (size_t)MATE * 4;       // 702,464
  const size_t perBO = (size_t)196 * 784 * 2;      // 307,328
  const size_t perB = perB5 + perBX + perBS + perBO;  // 3,073,280
  const size_t WB = (size_t)784 * 784 * 2;         // 1,229,312 per weight
  const size_t fixed = 4 * WB + 2 * 4 * perHeadB + 1024;  // ~5.6 MB

  int CB = 256;
  while (CB > 1 && (size_t)CB * perB + fixed > ws_size) CB >>= 1;
  if ((size_t)CB * perB + fixed > ws_size) return;  // ws hopeless (<~9MB)

  char* ws = (char*)d_ws;
  const size_t bufSz = (size_t)CB * 4 * perHeadB;  // one bf16 mat buffer
  bf16*  Qb  = (bf16*)(ws);
  bf16*  Kb  = (bf16*)(ws + bufSz);
  bf16*  Qth = (bf16*)(ws + 2 * bufSz);
  bf16*  Vtb = (bf16*)(ws + 3 * bufSz);
  bf16*  Qtl = (bf16*)(ws + 4 * bufSz);
  bf16*  XB  = (bf16*)(ws + 5 * bufSz);
  float* S   = (float*)(ws + 5 * bufSz + (size_t)CB * perBX);
  bf16*  O   = (bf16*)(ws + 5 * bufSz + (size_t)CB * (perBX + perBS));
  char*  fx  = ws + 5 * bufSz + (size_t)CB * (perBX + perBS + perBO);
  bf16* WqB = (bf16*)(fx);
  bf16* WkB = (bf16*)(fx + WB);
  bf16* WvB = (bf16*)(fx + 2 * WB);
  bf16* WoB = (bf16*)(fx + 3 * WB);
  bf16* CPh = (bf16*)(fx + 4 * WB);
  bf16* CPl = (bf16*)(fx + 4 * WB + 4 * perHeadB);

  // One-time prep (re-done every call; ws is re-poisoned by the harness).
  const long nwords = (long)CB * 5 * 4 * 196 * 14;
  zero_pads<<<(int)((nwords + 255) / 256), 256, 0, stream>>>(ws, nwords);
  build_cp<<<686, 256, 0, stream>>>(rh, rw, CPh, CPl);
  const long w4 = 784L * 784 / 4;  // 153,664
  cvt_f2b<<<(int)((w4 + 255) / 256), 256, 0, stream>>>(Wq, WqB, w4);
  cvt_f2b<<<(int)((w4 + 255) / 256), 256, 0, stream>>>(Wk, WkB, w4);
  cvt_f2b<<<(int)((w4 + 255) / 256), 256, 0, stream>>>(Wv, WvB, w4);
  cvt_f2b<<<(int)((w4 + 255) / 256), 256, 0, stream>>>(Wo, WoB, w4);

  for (int c0 = 0; c0 < 256; c0 += CB) {
    const int M = CB * 196;
    const int gx = (M + 127) / 128;
    const long x4 = (long)M * 784 / 4;
    cvt_f2b<<<(int)((x4 + 255) / 256), 256, 0, stream>>>(
        x + (size_t)c0 * 196 * 784, XB, x4);

    dim3 gp(gx, 7);
    gemm_proj<0><<<gp, 256, 0, stream>>>(XB, WqB, bq, Qb, Qth, Qtl, nullptr, M);
    gemm_proj<1><<<gp, 256, 0, stream>>>(XB, WkB, bk, Kb, nullptr, nullptr, nullptr, M);
    gemm_proj<2><<<gp, 256, 0, stream>>>(XB, WvB, bv, nullptr, Vtb, nullptr, nullptr, M);

    dim3 ga(2, 2, CB * 4);
    attn_score<<<ga, 256, 0, stream>>>(Qb, Kb, CPh, CPl, Qth, Qtl, S);
    softmax_k<<<dim3(49, CB * 4), 256, 0, stream>>>(S);
    attn_pv<<<ga, 256, 0, stream>>>(S, Vtb, O);

    gemm_proj<3><<<gp, 256, 0, stream>>>(O, WoB, bo, nullptr, nullptr, nullptr,
                                         out + (size_t)c0 * 196 * 784, M);
  }
}